// Round 12
// baseline (318.196 us; speedup 1.0000x reference)
//
#include <hip/hip_runtime.h>
#include <stdint.h>

#define N_V   4096
#define T_PER 4
#define NT    16384
#define D_K   256
#define SCALE 10.0f   // 1/temperature
#define LOG2E 1.44269504088896340736f
#define LN2   0.69314718055994530942f
#define NBLK  4096    // k_fused grid = 64 x 64
#define TAIL  128     // last-128 finishers run the post phase

#if defined(__has_builtin)
#if __has_builtin(__builtin_amdgcn_exp2f)
#define EXP2F(x) __builtin_amdgcn_exp2f(x)
#endif
#endif
#ifndef EXP2F
#define EXP2F(x) exp2f(x)
#endif

typedef __bf16 bf16x8 __attribute__((ext_vector_type(8)));
typedef float  f32x4  __attribute__((ext_vector_type(4)));

__device__ __forceinline__ unsigned short f2bf(float f) {
  uint32_t u = __float_as_uint(f);
  u = (u + 0x7fffu + ((u >> 16) & 1u)) >> 16;   // RNE
  return (unsigned short)u;
}

// ---------------- A: fused convert + diagonal dots (reads v,t exactly once) ---------------
// A-side bf16 carries SCALE*LOG2E so GEMM scores come out in log2 domain.
// Also zeroes d_out (for tail atomics) and the done-counter (d_ws is poisoned every launch).
__global__ void k_prep(const float* __restrict__ v, const float* __restrict__ t,
                       unsigned short* __restrict__ Abf, unsigned short* __restrict__ Bbf,
                       float* __restrict__ thr, float* __restrict__ nom,
                       float* __restrict__ out, uint32_t* __restrict__ done) {
  const int tid = threadIdx.x, l = tid & 63, w = tid >> 6;
  const int i = blockIdx.x * 4 + w;            // one wave per video
  if (blockIdx.x == 0 && tid < 5) out[tid] = 0.0f;
  if (blockIdx.x == 0 && tid == 5) *done = 0u;
  const float AS = SCALE * LOG2E;

  float4 a = ((const float4*)(v + (size_t)i * D_K))[l];
  ushort4 oa;
  oa.x = f2bf(a.x * AS); oa.y = f2bf(a.y * AS);
  oa.z = f2bf(a.z * AS); oa.w = f2bf(a.w * AS);
  ((ushort4*)(Abf + (size_t)i * D_K))[l] = oa;

  float tv[T_PER];
#pragma unroll
  for (int tt = 0; tt < T_PER; ++tt) {
    float4 b = ((const float4*)(t + (size_t)(i * T_PER + tt) * D_K))[l];
    ushort4 ob;
    ob.x = f2bf(b.x); ob.y = f2bf(b.y); ob.z = f2bf(b.z); ob.w = f2bf(b.w);
    ((ushort4*)(Bbf + (size_t)(i * T_PER + tt) * D_K))[l] = ob;
    float d = a.x * b.x + a.y * b.y + a.z * b.z + a.w * b.w;
#pragma unroll
    for (int s = 1; s < 64; s <<= 1) d += __shfl_xor(d, s);
    tv[tt] = d * SCALE;                        // natural-domain score
  }
  if (l == 0) {
    ((float4*)thr)[i] = make_float4(tv[0] * LOG2E, tv[1] * LOG2E,
                                    tv[2] * LOG2E, tv[3] * LOG2E);
    float m = fmaxf(fmaxf(tv[0], tv[1]), fmaxf(tv[2], tv[3]));
    float e = __expf(tv[0] - m) + __expf(tv[1] - m) + __expf(tv[2] - m) + __expf(tv[3] - m);
    nom[i] = m + __logf(e);
  }
}

// ---------------- B: r11-verbatim fused GEMM + LSE/rank epilogue + dynamic-tail post -------
// GEMM phase is bit-identical to r11 (126.8us, absmax 6e-5). New: instead of a separate
// k_post dispatch, every block publishes its partials (syncthreads drains stores to this
// XCD's L2; thread-0 __threadfence() writes L2 back to the device coherence point), then
// takes an atomic completion ticket. The last TAIL finishers each run one post-chunk after
// spinning for done==NBLK. Deadlock-free: a ticket >= NBLK-TAIL implies >= NBLK-TAIL
// blocks completed, so >= NBLK-TAIL-128 slots freed -> the whole grid has been dispatched;
// stragglers are resident and running. Readers touch the partial buffers for the first
// time, so post-writeback L3/HBM data is what they fetch (no stale-cache hazard).
__device__ __forceinline__ void gld16(const void* g, void* l) {
  __builtin_amdgcn_global_load_lds((const __attribute__((address_space(1))) void*)g,
                                   (__attribute__((address_space(3))) void*)l,
                                   16, 0, 0);
}

__global__ __launch_bounds__(256) void k_fused(
    const unsigned short* __restrict__ Abf, const unsigned short* __restrict__ Bbf,
    const float* __restrict__ thr, const float* __restrict__ nom,
    float* __restrict__ pmax, float* __restrict__ psum, uint4* __restrict__ pcnt,
    float* __restrict__ cmax, float* __restrict__ csum,
    uint32_t* __restrict__ done, float* __restrict__ out) {
  __shared__ __align__(16) unsigned short As[64 * 256];   // 32 KB, swizzled full-K A tile
  __shared__ float4   thrS[64];
  __shared__ float    rowMw[4][64], rowEw[4][64];
  __shared__ uint32_t rowCw[4][64];
  // post-phase scratch (disjoint from the above; only TAIL blocks use it)
  __shared__ float Qm[2][128], Qs[2][128];
  __shared__ float colmL[128], colsL[128];
  __shared__ uint32_t ticketS;

  const int ct = blockIdx.x, rt = blockIdx.y;
  const int row0 = rt * 64, col0 = ct * 256;
  const int tid = threadIdx.x;
  const int l = tid & 63, w = tid >> 6;
  const int quad = l >> 4, nl = l & 15;

  if (tid < 64) thrS[tid] = ((const float4*)thr)[row0 + tid];

  // stage A once: 32 groups of 1024 B; lane l = lr*8+lc writes 16B chunk (lc^lr) of row lr
  const int lr = l >> 3, lc7 = l & 7, sc = lc7 ^ lr;
#pragma unroll
  for (int it = 0; it < 8; ++it) {
    int g = w * 8 + it;
    int rs = g >> 2, ks = g & 3;
    const unsigned short* ga = Abf + (size_t)(row0 + rs * 8 + lr) * D_K + ks * 64 + sc * 8;
    gld16(ga, (char*)As + g * 1024);
  }

  f32x4 acc[4][4];
#pragma unroll
  for (int i = 0; i < 4; ++i)
#pragma unroll
    for (int j = 0; j < 4; ++j) acc[i][j] = {0.f, 0.f, 0.f, 0.f};

  const unsigned short* pB[4];
#pragma unroll
  for (int j = 0; j < 4; ++j)
    pB[j] = Bbf + (size_t)(col0 + w * 64 + j * 16 + nl) * D_K + quad * 8;

  __syncthreads();   // the ONLY barrier before the epilogue

  bf16x8 bv[2][4];
#pragma unroll
  for (int j = 0; j < 4; ++j) bv[0][j] = *(const bf16x8*)(pB[j]);

#pragma unroll
  for (int c = 0; c < 8; ++c) {                 // 8 chunks of K=32, B dbuf from global/L2
    const int cur = c & 1;
    if (c < 7) {
#pragma unroll
      for (int j = 0; j < 4; ++j)
        bv[cur ^ 1][j] = *(const bf16x8*)(pB[j] + (c + 1) * 32);
    }
    bf16x8 af[4];
#pragma unroll
    for (int i = 0; i < 4; ++i) {
      int r = i * 16 + nl;
      int rb = r & 7;
      int grp = (r >> 3) * 4 + (c >> 1);
      int cc = ((((c & 1) << 2) | quad) ^ rb);
      af[i] = *(const bf16x8*)((const char*)As + grp * 1024 + (rb * 8 + cc) * 16);
    }
#pragma unroll
    for (int i = 0; i < 4; ++i)
#pragma unroll
      for (int j = 0; j < 4; ++j)
        acc[i][j] = __builtin_amdgcn_mfma_f32_16x16x32_bf16(af[i], bv[cur][j],
                                                            acc[i][j], 0, 0, 0);
  }

  // ============ epilogue (scores in log2 domain; C/D: col = nl, row = quad*4 + reg) =======
  uint32_t cnt[4][4];
#pragma unroll
  for (int i = 0; i < 4; ++i)
#pragma unroll
    for (int r = 0; r < 4; ++r) {
      float4 th = thrS[i * 16 + quad * 4 + r];
      uint32_t c = 0;
#pragma unroll
      for (int j = 0; j < 4; ++j) {
        float s = acc[i][j][r];
        c += (uint32_t)(s > th.x);
        c += (uint32_t)(s > th.y) << 8;
        c += (uint32_t)(s > th.z) << 16;
        c += (uint32_t)(s > th.w) << 24;
      }
      cnt[i][r] = c;
    }

  // row partials (wave's 64-col strip): per-row max (guarantees e >= 1), exp2-sum, count
#pragma unroll
  for (int i = 0; i < 4; ++i)
#pragma unroll
    for (int r = 0; r < 4; ++r) {
      float m = fmaxf(fmaxf(acc[i][0][r], acc[i][1][r]), fmaxf(acc[i][2][r], acc[i][3][r]));
#pragma unroll
      for (int d = 1; d < 16; d <<= 1) m = fmaxf(m, __shfl_xor(m, d));
      float e = EXP2F(acc[i][0][r] - m) + EXP2F(acc[i][1][r] - m)
              + EXP2F(acc[i][2][r] - m) + EXP2F(acc[i][3][r] - m);
      uint32_t c = cnt[i][r];
#pragma unroll
      for (int d = 1; d < 16; d <<= 1) { e += __shfl_xor(e, d); c += __shfl_xor(c, d); }
      if (nl == 0) {
        int row = i * 16 + quad * 4 + r;
        rowMw[w][row] = m; rowEw[w][row] = e; rowCw[w][row] = c;   // fields <= 64, no ovf
      }
    }

  // col partials: whole 64-row column lives in this wave -> direct global write
#pragma unroll
  for (int j = 0; j < 4; ++j) {
    float m = -3.0e38f;
#pragma unroll
    for (int i = 0; i < 4; ++i)
#pragma unroll
      for (int r = 0; r < 4; ++r) m = fmaxf(m, acc[i][j][r]);
    m = fmaxf(m, __shfl_xor(m, 16));
    m = fmaxf(m, __shfl_xor(m, 32));
    float e = 0.f;
#pragma unroll
    for (int i = 0; i < 4; ++i)
#pragma unroll
      for (int r = 0; r < 4; ++r) e += EXP2F(acc[i][j][r] - m);
    e += __shfl_xor(e, 16);
    e += __shfl_xor(e, 32);
    if (quad == 0) {
      int colg = col0 + w * 64 + j * 16 + nl;
      size_t gi = (size_t)rt * NT + colg;
      cmax[gi] = m; csum[gi] = e;
    }
  }
  __syncthreads();

  // combine the 4 col-strips per row (counts unpacked to 32-bit: 4x64 = 256 > 8-bit)
  if (tid < 64) {
    float M0 = rowMw[0][tid], M1 = rowMw[1][tid], M2 = rowMw[2][tid], M3 = rowMw[3][tid];
    float Mx = fmaxf(fmaxf(M0, M1), fmaxf(M2, M3));
    float Sx = rowEw[0][tid] * EXP2F(M0 - Mx) + rowEw[1][tid] * EXP2F(M1 - Mx)
             + rowEw[2][tid] * EXP2F(M2 - Mx) + rowEw[3][tid] * EXP2F(M3 - Mx);
    uint32_t c0 = 0, c1 = 0, c2 = 0, c3 = 0;
#pragma unroll
    for (int ww = 0; ww < 4; ++ww) {
      uint32_t cc = rowCw[ww][tid];
      c0 += cc & 0xffu; c1 += (cc >> 8) & 0xffu;
      c2 += (cc >> 16) & 0xffu; c3 += cc >> 24;
    }
    size_t gi = (size_t)ct * N_V + row0 + tid;
    pmax[gi] = Mx; psum[gi] = Sx; pcnt[gi] = make_uint4(c0, c1, c2, c3);
  }

  // ================= dynamic tail: last TAIL finishers run the post phase =================
  __syncthreads();                       // all waves' stores drained to this XCD's L2
  if (tid == 0) {
    __threadfence();                     // L2 writeback to device coherence point
    ticketS = atomicAdd(done, 1u);       // device-scope completion ticket
  }
  __syncthreads();
  const uint32_t ticket = ticketS;
  if (ticket < NBLK - TAIL) return;      // block-uniform
  const int cb = (int)(ticket - (NBLK - TAIL));   // post chunk in [0, TAIL)

  if (tid == 0) {
    while (__hip_atomic_load(done, __ATOMIC_RELAXED, __HIP_MEMORY_SCOPE_AGENT) < NBLK)
      __builtin_amdgcn_s_sleep(8);
    __threadfence();                     // acquire
  }
  __syncthreads();

  // ---- post chunk cb (r11 k_post body): cols [cb*128,+128), rows [cb*32,+32) ----
  {
    int c = tid & 127, h = tid >> 7;
    size_t col = (size_t)cb * 128 + c;
    float M = -3.0e38f, Ssum = 0.f;
    for (int k = 0; k < 32; ++k) {
      size_t idx = (size_t)(h * 32 + k) * NT + col;
      float m = cmax[idx], s = csum[idx];
      float nM = fmaxf(M, m);
      Ssum = Ssum * EXP2F(M - nM) + s * EXP2F(m - nM);
      M = nM;
    }
    Qm[h][c] = M; Qs[h][c] = Ssum;
  }
  __syncthreads();
  if (tid < 128) {
    float M0 = Qm[0][tid], M1 = Qm[1][tid];
    float Mx = fmaxf(M0, M1);
    colmL[tid] = Mx;
    colsL[tid] = Qs[0][tid] * EXP2F(M0 - Mx) + Qs[1][tid] * EXP2F(M1 - Mx);
  }
  __syncthreads();

  if (tid < 32) {
    int row = cb * 32 + tid;
    float M = -3.0e38f, Ssum = 0.f;
    uint32_t c0 = 0, c1 = 0, c2 = 0, c3 = 0;
    for (int k = 0; k < 64; ++k) {
      size_t idx = (size_t)k * N_V + row;
      float m = pmax[idx], s = psum[idx];
      uint4 cc = pcnt[idx];
      float nM = fmaxf(M, m);
      Ssum = Ssum * EXP2F(M - nM) + s * EXP2F(m - nM);
      M = nM;
      c0 += cc.x; c1 += cc.y; c2 += cc.z; c3 += cc.w;
    }
    float cm0 = colmL[tid * 4 + 0], cm1 = colmL[tid * 4 + 1];
    float cm2 = colmL[tid * 4 + 2], cm3 = colmL[tid * 4 + 3];
    float cs0 = colsL[tid * 4 + 0], cs1 = colsL[tid * 4 + 1];
    float cs2 = colsL[tid * 4 + 2], cs3 = colsL[tid * 4 + 3];
    float Mp = fmaxf(M, fmaxf(fmaxf(cm0, cm1), fmaxf(cm2, cm3)));
    float tot = Ssum * EXP2F(M - Mp)
              + cs0 * EXP2F(cm0 - Mp) + cs1 * EXP2F(cm1 - Mp)
              + cs2 * EXP2F(cm2 - Mp) + cs3 * EXP2F(cm3 - Mp);
    float ll = LN2 * (Mp + __log2f(tot)) - nom[row];
    float ar  = (float)(c0 + c1 + c2 + c3) * 0.25f;
    float r1  = (float)((c0 < 1u) + (c1 < 1u) + (c2 < 1u) + (c3 < 1u)) * 0.25f;
    float r5  = (float)((c0 < 5u) + (c1 < 5u) + (c2 < 5u) + (c3 < 5u)) * 0.25f;
    float r10 = (float)((c0 < 10u) + (c1 < 10u) + (c2 < 10u) + (c3 < 10u)) * 0.25f;
    float vals[5] = {ll, r1, r5, r10, ar};
#pragma unroll
    for (int k = 0; k < 5; ++k) {
      float vv = vals[k];
#pragma unroll
      for (int d = 1; d < 32; d <<= 1) vv += __shfl_xor(vv, d);
      if (tid == 0) atomicAdd(&out[k], vv * (1.0f / N_V));
    }
  }
}

extern "C" void kernel_launch(void* const* d_in, const int* in_sizes, int n_in,
                              void* d_out, int out_size, void* d_ws, size_t ws_size,
                              hipStream_t stream) {
  const float* v = (const float*)d_in[0];
  const float* t = (const float*)d_in[1];
  char* p = (char*)d_ws;
  unsigned short* Abf = (unsigned short*)p; p += (size_t)N_V * D_K * 2;
  unsigned short* Bbf = (unsigned short*)p; p += (size_t)NT * D_K * 2;
  float* thr  = (float*)p;    p += (size_t)N_V * 4 * 4;
  float* nom  = (float*)p;    p += (size_t)N_V * 4;
  float* pmax = (float*)p;    p += (size_t)64 * N_V * 4;
  float* psum = (float*)p;    p += (size_t)64 * N_V * 4;
  uint4* pcnt = (uint4*)p;    p += (size_t)64 * N_V * 16;
  float* cmaxp = (float*)p;   p += (size_t)64 * NT * 4;
  float* csump = (float*)p;   p += (size_t)64 * NT * 4;
  uint32_t* done = (uint32_t*)p; p += 256;
  // total ws: ~24 MB

  k_prep<<<N_V / 4, 256, 0, stream>>>(v, t, Abf, Bbf, thr, nom, (float*)d_out, done);
  dim3 g(NT / 256, N_V / 64);                     // ct x rt = 64 x 64
  k_fused<<<g, 256, 0, stream>>>(Abf, Bbf, thr, nom, pmax, psum, pcnt, cmaxp, csump,
                                 done, (float*)d_out);
}